// Round 1
// baseline (393.242 us; speedup 1.0000x reference)
//
#include <hip/hip_runtime.h>

#define BS_ 32
#define A_  8400
#define C_  80
#define N_  48
#define K_  13
#define EPSF 1e-9f

// ---------------- Kernel A: per-(b,n) compute + top-k ----------------
__global__ __launch_bounds__(256) void tal_compute_topk(
    const float* __restrict__ pd_scores, const float* __restrict__ pd_bbox,
    const float* __restrict__ anc, const int* __restrict__ gt_labels,
    const float* __restrict__ gt_bbox, const float* __restrict__ mask_gt,
    float* __restrict__ overlaps, float* __restrict__ alignm, float* __restrict__ mask_pos)
{
    __shared__ float sm[A_];
    __shared__ float red_v[256];
    __shared__ int   red_i[256];
    __shared__ int   s_topk[K_];

    const int bn = blockIdx.x;
    const int b  = bn / N_;

    const float gx1 = gt_bbox[bn*4+0], gy1 = gt_bbox[bn*4+1];
    const float gx2 = gt_bbox[bn*4+2], gy2 = gt_bbox[bn*4+3];
    const int   lab = gt_labels[bn];
    const float mgt = mask_gt[bn];
    const float wg = gx2 - gx1;
    const float hg = gy2 - gy1 + EPSF;
    const float areag = wg * hg;

    const float4* pb = reinterpret_cast<const float4*>(pd_bbox) + (size_t)b * A_;
    const float*  ps = pd_scores + (size_t)b * A_ * C_ + lab;
    const float2* an = reinterpret_cast<const float2*>(anc);
    const size_t row = (size_t)bn * A_;

    for (int a = threadIdx.x; a < A_; a += 256) {
        float4 p = pb[a];
        float wp = p.z - p.x;
        float hp = p.w - p.y + EPSF;
        float iw = fmaxf(fminf(gx2, p.z) - fmaxf(gx1, p.x), 0.f);
        float ih = fmaxf(fminf(gy2, p.w) - fmaxf(gy1, p.y), 0.f);
        float inter = iw * ih;
        float uni = areag + wp * hp - inter + EPSF;
        float ov = fmaxf(inter / uni, 0.f);
        float sc = ps[(size_t)a * C_];
        float o2 = ov * ov;
        float al = sc * (o2 * o2 * o2);
        float2 ap = an[a];
        float mind = fminf(fminf(ap.x - gx1, ap.y - gy1), fminf(gx2 - ap.x, gy2 - ap.y));
        overlaps[row + a] = ov;
        alignm[row + a]   = al;
        mask_pos[row + a] = 0.f;
        sm[a] = (mind > EPSF) ? al : 0.f;
    }
    __syncthreads();

    // 13 rounds of block-wide argmax; ties -> lowest index (jax.lax.top_k stability)
    for (int k = 0; k < K_; ++k) {
        float bv = -1.f; int bi = 0x7fffffff;
        for (int a = threadIdx.x; a < A_; a += 256) {
            float v = sm[a];
            if (v > bv) { bv = v; bi = a; }   // strict > keeps lowest index within thread
        }
        red_v[threadIdx.x] = bv; red_i[threadIdx.x] = bi;
        __syncthreads();
        for (int s = 128; s > 0; s >>= 1) {
            if (threadIdx.x < s) {
                float v2 = red_v[threadIdx.x + s]; int i2 = red_i[threadIdx.x + s];
                float v1 = red_v[threadIdx.x];     int i1 = red_i[threadIdx.x];
                if (v2 > v1 || (v2 == v1 && i2 < i1)) {
                    red_v[threadIdx.x] = v2; red_i[threadIdx.x] = i2;
                }
            }
            __syncthreads();
        }
        if (threadIdx.x == 0) { int w = red_i[0]; s_topk[k] = w; sm[w] = -2.f; }
        __syncthreads();
    }

    // mask_pos = is_in_topk * mask_in_gts * mask_gt
    // (masked gt rows: counts trick -> all zero; handled by skipping when mgt<=0)
    if (threadIdx.x < K_ && mgt > 0.f) {
        int a = s_topk[threadIdx.x];
        float2 ap = an[a];
        float mind = fminf(fminf(ap.x - gx1, ap.y - gy1), fminf(gx2 - ap.x, gy2 - ap.y));
        if (mind > EPSF) mask_pos[row + a] = mgt;
    }
}

// ---------------- Kernel B: per-(b,a) multi-GT resolution + 4 outputs ----------------
__global__ __launch_bounds__(256) void tal_resolve(
    const float* __restrict__ overlaps, float* __restrict__ mask_pos,
    const int* __restrict__ gt_labels, const float* __restrict__ gt_bbox,
    float* __restrict__ o_labels, float* __restrict__ o_bbox,
    float* __restrict__ o_fg, float* __restrict__ o_tgi)
{
    const int idx = blockIdx.x * 256 + threadIdx.x;
    if (idx >= BS_ * A_) return;
    const int b = idx / A_;
    const int a = idx - b * A_;
    const size_t base = (size_t)b * N_ * A_ + a;

    float fg = 0.f;
    for (int n = 0; n < N_; ++n) fg += mask_pos[base + (size_t)n * A_];

    int tgi;
    if (fg > 1.f) {
        // argmax over n of overlaps (first max wins, like jnp.argmax)
        float bv = overlaps[base]; int bi = 0;
        for (int n = 1; n < N_; ++n) {
            float v = overlaps[base + (size_t)n * A_];
            if (v > bv) { bv = v; bi = n; }
        }
        for (int n = 0; n < N_; ++n)
            mask_pos[base + (size_t)n * A_] = (n == bi) ? 1.f : 0.f;
        fg = 1.f;
        tgi = bi;
    } else {
        float bv = mask_pos[base]; int bi = 0;
        for (int n = 1; n < N_; ++n) {
            float v = mask_pos[base + (size_t)n * A_];
            if (v > bv) { bv = v; bi = n; }
        }
        tgi = bi;
    }

    o_fg[idx]  = (fg > 0.f) ? 1.f : 0.f;
    o_tgi[idx] = (float)tgi;
    const int gi = b * N_ + tgi;
    o_labels[idx] = (float)gt_labels[gi];
    float4 gb = reinterpret_cast<const float4*>(gt_bbox)[gi];
    reinterpret_cast<float4*>(o_bbox)[idx] = gb;
}

// ---------------- Kernel C: per-(b,n) row maxes ----------------
__global__ __launch_bounds__(256) void tal_rowmax(
    const float* __restrict__ alignm, const float* __restrict__ overlaps,
    const float* __restrict__ mask_pos,
    float* __restrict__ pos_align, float* __restrict__ pos_ov)
{
    __shared__ float ra[256];
    __shared__ float ro[256];
    const int bn = blockIdx.x;
    const size_t row = (size_t)bn * A_;
    float ma = 0.f, mo = 0.f;
    for (int a = threadIdx.x; a < A_; a += 256) {
        float mp = mask_pos[row + a];
        ma = fmaxf(ma, alignm[row + a] * mp);
        mo = fmaxf(mo, overlaps[row + a] * mp);
    }
    ra[threadIdx.x] = ma; ro[threadIdx.x] = mo;
    __syncthreads();
    for (int s = 128; s > 0; s >>= 1) {
        if (threadIdx.x < s) {
            ra[threadIdx.x] = fmaxf(ra[threadIdx.x], ra[threadIdx.x + s]);
            ro[threadIdx.x] = fmaxf(ro[threadIdx.x], ro[threadIdx.x + s]);
        }
        __syncthreads();
    }
    if (threadIdx.x == 0) { pos_align[bn] = ra[0]; pos_ov[bn] = ro[0]; }
}

// ---------------- Kernel D1: per-(b,a) norm metric ----------------
__global__ __launch_bounds__(256) void tal_norm(
    const float* __restrict__ alignm, const float* __restrict__ mask_pos,
    const float* __restrict__ pos_align, const float* __restrict__ pos_ov,
    float* __restrict__ norm)
{
    const int idx = blockIdx.x * 256 + threadIdx.x;
    if (idx >= BS_ * A_) return;
    const int b = idx / A_;
    const int a = idx - b * A_;
    const size_t base = (size_t)b * N_ * A_ + a;
    float m = 0.f;
    for (int n = 0; n < N_; ++n) {
        float t = alignm[base + (size_t)n * A_] * mask_pos[base + (size_t)n * A_];
        t = t * pos_ov[b * N_ + n] / (pos_align[b * N_ + n] + EPSF);
        m = fmaxf(m, t);
    }
    norm[idx] = m;
}

// ---------------- Kernel D2: scatter target_scores ----------------
__global__ __launch_bounds__(256) void tal_scores(
    const float* __restrict__ norm, const float* __restrict__ o_labels,
    const float* __restrict__ o_fg, float* __restrict__ o_scores)
{
    const size_t idx = (size_t)blockIdx.x * 256 + threadIdx.x;
    if (idx >= (size_t)BS_ * A_ * C_) return;
    const size_t ba = idx / C_;
    const int c = (int)(idx - ba * C_);
    float v = 0.f;
    if (o_fg[ba] > 0.f && (int)o_labels[ba] == c) v = norm[ba];
    o_scores[idx] = v;
}

extern "C" void kernel_launch(void* const* d_in, const int* in_sizes, int n_in,
                              void* d_out, int out_size, void* d_ws, size_t ws_size,
                              hipStream_t stream) {
    const float* pd_scores = (const float*)d_in[0];
    const float* pd_bbox   = (const float*)d_in[1];
    const float* anc       = (const float*)d_in[2];
    const int*   gt_labels = (const int*)d_in[3];
    const float* gt_bbox   = (const float*)d_in[4];
    const float* mask_gt   = (const float*)d_in[5];

    const size_t BA  = (size_t)BS_ * A_;          // 268800
    const size_t BNA = (size_t)BS_ * N_ * A_;     // 12902400

    // output layout (flat concat, float32)
    float* out      = (float*)d_out;
    float* o_labels = out;
    float* o_bbox   = out + BA;
    float* o_scores = out + BA + BA * 4;
    float* o_fg     = o_scores + BA * C_;
    float* o_tgi    = o_fg + BA;

    // workspace layout
    float* ws        = (float*)d_ws;
    float* overlaps  = ws;                  // BNA
    float* alignm    = overlaps + BNA;      // BNA
    float* mask_pos  = alignm + BNA;        // BNA
    float* pos_align = mask_pos + BNA;      // BS*N
    float* pos_ov    = pos_align + BS_*N_;  // BS*N
    float* norm      = pos_ov + BS_*N_;     // BA

    tal_compute_topk<<<BS_ * N_, 256, 0, stream>>>(
        pd_scores, pd_bbox, anc, gt_labels, gt_bbox, mask_gt,
        overlaps, alignm, mask_pos);

    tal_resolve<<<(int)((BA + 255) / 256), 256, 0, stream>>>(
        overlaps, mask_pos, gt_labels, gt_bbox,
        o_labels, o_bbox, o_fg, o_tgi);

    tal_rowmax<<<BS_ * N_, 256, 0, stream>>>(
        alignm, overlaps, mask_pos, pos_align, pos_ov);

    tal_norm<<<(int)((BA + 255) / 256), 256, 0, stream>>>(
        alignm, mask_pos, pos_align, pos_ov, norm);

    tal_scores<<<(int)(((size_t)BS_ * A_ * C_ + 255) / 256), 256, 0, stream>>>(
        norm, o_labels, o_fg, o_scores);
}

// Round 4
// 268.076 us; speedup vs baseline: 1.4669x; 1.4669x over previous
//
#include <hip/hip_runtime.h>

#define BS_ 32
#define A_  8400
#define C_  80
#define N_  48
#define K_  13
#define EPSF 1e-9f
#define CH_ 128      // anchors per chunk in tal_metrics
#define NCH_ 66      // ceil(8400/128)
#define SEGS_ 33     // 33*256 = 8448 padded row

// ---------------- Kernel 1: metrics[b][n][a] = score_gather * iou^6 * in_gt ----------------
__global__ __launch_bounds__(256) void tal_metrics(
    const float* __restrict__ ps, const float* __restrict__ pb,
    const float* __restrict__ anc, const int* __restrict__ gl,
    const float* __restrict__ gb, float* __restrict__ metrics)
{
    __shared__ float  s_sc[CH_ * 81];
    __shared__ float4 s_pb[CH_];
    __shared__ float2 s_anc[CH_];
    __shared__ float4 s_gt[N_];
    __shared__ int    s_lab[N_];

    const int b  = blockIdx.y;
    const int a0 = blockIdx.x * CH_;
    const int ca = min(CH_, A_ - a0);
    const int tid = threadIdx.x;

    if (tid < N_) {
        s_gt[tid]  = reinterpret_cast<const float4*>(gb)[b * N_ + tid];
        s_lab[tid] = gl[b * N_ + tid];
    }
    if (tid < ca) {
        s_pb[tid]  = reinterpret_cast<const float4*>(pb)[(size_t)b * A_ + a0 + tid];
        s_anc[tid] = reinterpret_cast<const float2*>(anc)[a0 + tid];
    }
    // stage scores coalesced: ca*80 floats contiguous in global
    const float4* src = reinterpret_cast<const float4*>(ps + ((size_t)b * A_ + a0) * C_);
    const int nf4 = ca * 20;
    for (int i = tid; i < nf4; i += 256) {
        float4 v = src[i];
        int a_l = i / 20, c = (i % 20) * 4;
        float* d = &s_sc[a_l * 81 + c];
        d[0] = v.x; d[1] = v.y; d[2] = v.z; d[3] = v.w;
    }
    __syncthreads();

    const int a_l = tid & (CH_ - 1);
    const int nh  = tid >> 7;           // 0 or 1
    if (a_l < ca) {
        float4 p = s_pb[a_l];
        float2 ap = s_anc[a_l];
        float wp = p.z - p.x, hp = p.w - p.y + EPSF;
        float areap = wp * hp;
        size_t outbase = (size_t)b * N_ * A_ + a0 + a_l;
        for (int n = nh; n < N_; n += 2) {
            float4 g = s_gt[n];
            float wg = g.z - g.x, hg = g.w - g.y + EPSF;
            float iw = fmaxf(fminf(g.z, p.z) - fmaxf(g.x, p.x), 0.f);
            float ih = fmaxf(fminf(g.w, p.w) - fmaxf(g.y, p.y), 0.f);
            float inter = iw * ih;
            float uni = wg * hg + areap - inter + EPSF;
            float ov = fmaxf(inter / uni, 0.f);
            float sc = s_sc[a_l * 81 + s_lab[n]];
            float o2 = ov * ov;
            float al = sc * (o2 * o2 * o2);
            float mind = fminf(fminf(ap.x - g.x, ap.y - g.y), fminf(g.z - ap.x, g.w - ap.y));
            metrics[outbase + (size_t)n * A_] = (mind > EPSF) ? al : 0.f;
        }
    }
}

// ---------------- Kernel 2: per-(b,n) top-13 -> sparse atomics ----------------
__global__ __launch_bounds__(256) void tal_topk(
    const float* __restrict__ metrics, const float* __restrict__ anc,
    const float* __restrict__ gb, const float* __restrict__ mask_gt,
    int* __restrict__ fg_count, int* __restrict__ assigned_min)
{
    __shared__ __align__(16) float sm[SEGS_ * 256];
    __shared__ float seg_max[SEGS_];
    __shared__ int   s_topk[K_];

    const int bn = blockIdx.x;
    const int b  = bn / N_;
    const int n_idx = bn - b * N_;
    const int tid = threadIdx.x;
    const int lane = tid & 63;
    const int wid  = tid >> 6;

    const float4 g = reinterpret_cast<const float4*>(gb)[bn];
    const float mgt = mask_gt[bn];

    // load row (coalesced) + pad
    const float4* row4 = reinterpret_cast<const float4*>(metrics + (size_t)bn * A_);
    float4* sm4 = reinterpret_cast<float4*>(sm);
    for (int i = tid; i < A_ / 4; i += 256) sm4[i] = row4[i];
    if (tid < SEGS_ * 256 - A_) sm[A_ + tid] = -1.f;
    __syncthreads();

    // per-segment maxes (segment = 256 contiguous floats = 64 float4)
    for (int s = wid; s < SEGS_; s += 4) {
        float4 v = sm4[s * 64 + lane];
        float m = fmaxf(fmaxf(v.x, v.y), fmaxf(v.z, v.w));
        for (int o = 32; o; o >>= 1) m = fmaxf(m, __shfl_xor(m, o));
        if (lane == 0) seg_max[s] = m;
    }
    __syncthreads();

    if (wid == 0) {
        for (int k = 0; k < K_; ++k) {
            // winner segment (ties -> lowest seg)
            float v = (lane < SEGS_) ? seg_max[lane] : -3.f;
            int   i = lane;
            for (int o = 32; o; o >>= 1) {
                float v2 = __shfl_xor(v, o); int i2 = __shfl_xor(i, o);
                if (v2 > v || (v2 == v && i2 < i)) { v = v2; i = i2; }
            }
            const int s = i;
            // scan winner segment, argmax (ties -> lowest index)
            float4 q = sm4[s * 64 + lane];
            float bv = q.x; int bj = 0;
            if (q.y > bv) { bv = q.y; bj = 1; }
            if (q.z > bv) { bv = q.z; bj = 2; }
            if (q.w > bv) { bv = q.w; bj = 3; }
            float wv = bv; int wi = (s << 8) + (lane << 2) + bj;
            for (int o = 32; o; o >>= 1) {
                float v2 = __shfl_xor(wv, o); int i2 = __shfl_xor(wi, o);
                if (v2 > wv || (v2 == wv && i2 < wi)) { wv = v2; wi = i2; }
            }
            // owner lane removes winner and updates its local copy
            if (((wi >> 2) & 63) == lane) {
                sm[wi] = -2.f;
                int comp = wi & 3;
                if (comp == 0) q.x = -2.f; else if (comp == 1) q.y = -2.f;
                else if (comp == 2) q.z = -2.f; else q.w = -2.f;
            }
            float nm = fmaxf(fmaxf(q.x, q.y), fmaxf(q.z, q.w));
            for (int o = 32; o; o >>= 1) nm = fmaxf(nm, __shfl_xor(nm, o));
            if (lane == 0) { seg_max[s] = nm; s_topk[k] = wi; }
        }
    }
    __syncthreads();

    if (tid < K_ && mgt > 0.f) {
        int a = s_topk[tid];
        float2 ap = reinterpret_cast<const float2*>(anc)[a];
        float mind = fminf(fminf(ap.x - g.x, ap.y - g.y), fminf(g.z - ap.x, g.w - ap.y));
        if (mind > EPSF) {
            atomicAdd(&fg_count[b * A_ + a], 1);
            atomicMin(&assigned_min[b * A_ + a], n_idx);
        }
    }
}

// ---------------- Kernel 3: per-(b,a) resolution + small outputs ----------------
__device__ __forceinline__ float iou_f(float4 g, float4 p) {
    float wg = g.z - g.x, hg = g.w - g.y + EPSF;
    float wp = p.z - p.x, hp = p.w - p.y + EPSF;
    float iw = fmaxf(fminf(g.z, p.z) - fmaxf(g.x, p.x), 0.f);
    float ih = fmaxf(fminf(g.w, p.w) - fmaxf(g.y, p.y), 0.f);
    float inter = iw * ih;
    float uni = wg * hg + wp * hp - inter + EPSF;
    return fmaxf(inter / uni, 0.f);
}

__global__ __launch_bounds__(256) void tal_resolve(
    const float* __restrict__ metrics, const float* __restrict__ pb,
    const float* __restrict__ gb, const int* __restrict__ gl,
    const float* __restrict__ ps,
    const int* __restrict__ fg_count, const int* __restrict__ assigned_min,
    float* __restrict__ o_labels, float* __restrict__ o_bbox,
    float* __restrict__ o_fg, float* __restrict__ o_tgi,
    float* __restrict__ norm_num,
    unsigned int* __restrict__ pos_al, unsigned int* __restrict__ pos_ov)
{
    __shared__ float4 s_gt[N_];
    __shared__ int    s_lab[N_];
    const int b = blockIdx.y;
    const int a = blockIdx.x * 256 + threadIdx.x;
    if (threadIdx.x < N_) {
        s_gt[threadIdx.x]  = reinterpret_cast<const float4*>(gb)[b * N_ + threadIdx.x];
        s_lab[threadIdx.x] = gl[b * N_ + threadIdx.x];
    }
    __syncthreads();
    if (a >= A_) return;

    const int idx = b * A_ + a;
    const int fg = fg_count[idx];
    float al = 0.f, ov = 0.f, fgo = 0.f;
    int tgi = 0;
    if (fg == 1) {
        tgi = assigned_min[idx];
        al = metrics[((size_t)b * N_ + tgi) * A_ + a];
        float4 p = reinterpret_cast<const float4*>(pb)[(size_t)b * A_ + a];
        ov = iou_f(s_gt[tgi], p);
        fgo = 1.f;
    } else if (fg > 1) {
        float4 p = reinterpret_cast<const float4*>(pb)[(size_t)b * A_ + a];
        float bv = -1.f; int bi = 0;
        for (int n = 0; n < N_; ++n) {
            float v = iou_f(s_gt[n], p);
            if (v > bv) { bv = v; bi = n; }
        }
        tgi = bi; ov = bv;
        float sc = ps[((size_t)b * A_ + a) * C_ + s_lab[bi]];
        float o2 = ov * ov;
        al = sc * (o2 * o2 * o2);
        fgo = 1.f;
    }
    if (fgo > 0.f) {
        atomicMax(&pos_al[b * N_ + tgi], __float_as_uint(al));
        atomicMax(&pos_ov[b * N_ + tgi], __float_as_uint(ov));
    }
    o_fg[idx] = fgo;
    o_tgi[idx] = (float)tgi;
    o_labels[idx] = (float)s_lab[tgi];
    reinterpret_cast<float4*>(o_bbox)[idx] = s_gt[tgi];
    norm_num[idx] = al;
}

// ---------------- Kernel 4: target_scores scatter (coalesced float4) ----------------
__global__ __launch_bounds__(256) void tal_scores(
    const float* __restrict__ o_labels, const float* __restrict__ o_fg,
    const float* __restrict__ o_tgi, const float* __restrict__ norm_num,
    const unsigned int* __restrict__ pos_al, const unsigned int* __restrict__ pos_ov,
    float* __restrict__ o_scores)
{
    const int idx = blockIdx.x * 256 + threadIdx.x;   // over BA*20 float4s
    if (idx >= BS_ * A_ * (C_ / 4)) return;
    const int ba = idx / 20;
    const int c0 = (idx % 20) * 4;
    float4 v = {0.f, 0.f, 0.f, 0.f};
    if (o_fg[ba] > 0.f) {
        int lab = (int)o_labels[ba];
        if (lab >= c0 && lab < c0 + 4) {
            int b = ba / A_;
            int tgi = (int)o_tgi[ba];
            float pa = __uint_as_float(pos_al[b * N_ + tgi]);
            float po = __uint_as_float(pos_ov[b * N_ + tgi]);
            float nrm = norm_num[ba] * po / (pa + EPSF);
            if (lab == c0) v.x = nrm; else if (lab == c0 + 1) v.y = nrm;
            else if (lab == c0 + 2) v.z = nrm; else v.w = nrm;
        }
    }
    reinterpret_cast<float4*>(o_scores)[idx] = v;
}

extern "C" void kernel_launch(void* const* d_in, const int* in_sizes, int n_in,
                              void* d_out, int out_size, void* d_ws, size_t ws_size,
                              hipStream_t stream) {
    const float* pd_scores = (const float*)d_in[0];
    const float* pd_bbox   = (const float*)d_in[1];
    const float* anc       = (const float*)d_in[2];
    const int*   gt_labels = (const int*)d_in[3];
    const float* gt_bbox   = (const float*)d_in[4];
    const float* mask_gt   = (const float*)d_in[5];

    const size_t BA  = (size_t)BS_ * A_;          // 268800
    const size_t BNA = (size_t)BS_ * N_ * A_;     // 12902400
    const int    BN  = BS_ * N_;                  // 1536

    float* out      = (float*)d_out;
    float* o_labels = out;
    float* o_bbox   = out + BA;
    float* o_scores = out + BA * 5;
    float* o_fg     = o_scores + BA * C_;
    float* o_tgi    = o_fg + BA;

    float* metrics        = (float*)d_ws;                    // BNA
    int*   fg_count       = (int*)(metrics + BNA);           // BA
    unsigned int* pos_al  = (unsigned int*)(fg_count + BA);  // BN
    unsigned int* pos_ov  = pos_al + BN;                     // BN
    int*   assigned_min   = (int*)(pos_ov + BN);             // BA
    float* norm_num       = (float*)(assigned_min + BA);     // BA

    hipMemsetAsync(fg_count, 0, (BA + 2 * BN) * sizeof(int), stream);
    hipMemsetAsync(assigned_min, 0x7f, BA * sizeof(int), stream);

    tal_metrics<<<dim3(NCH_, BS_), 256, 0, stream>>>(
        pd_scores, pd_bbox, anc, gt_labels, gt_bbox, metrics);

    tal_topk<<<BN, 256, 0, stream>>>(
        metrics, anc, gt_bbox, mask_gt, fg_count, assigned_min);

    tal_resolve<<<dim3((A_ + 255) / 256, BS_), 256, 0, stream>>>(
        metrics, pd_bbox, gt_bbox, gt_labels, pd_scores,
        fg_count, assigned_min,
        o_labels, o_bbox, o_fg, o_tgi, norm_num, pos_al, pos_ov);

    tal_scores<<<(int)((BA * 20 + 255) / 256), 256, 0, stream>>>(
        o_labels, o_fg, o_tgi, norm_num, pos_al, pos_ov, o_scores);
}